// Round 8
// baseline (283.696 us; speedup 1.0000x reference)
//
#include <hip/hip_runtime.h>
#include <hip/hip_bf16.h>

#define NS 200000
#define KF 9
#define CC 64
#define RPB 128                       // rows per block (4 waves x 32 rows)
#define NB ((NS + RPB - 1) / RPB)     // 1563 (last block: 64 valid rows)

typedef __bf16 bf16_t;
typedef __bf16 bf16x8 __attribute__((ext_vector_type(8)));
typedef __bf16 bf16x4 __attribute__((ext_vector_type(4)));
typedef float f32x4 __attribute__((ext_vector_type(4)));

// ---------------- combined prep: x->bf16, pack W1/W2, zero stats+zrow ----------------
__global__ void k_prep(const float* __restrict__ x, const float* __restrict__ W1,
                       const float* __restrict__ W2, bf16_t* __restrict__ xb,
                       bf16_t* __restrict__ W1p, bf16_t* __restrict__ W2p,
                       float* __restrict__ stats /*256*/, float* __restrict__ zrow /*32*/) {
  const int b = blockIdx.x;
  const int tid = threadIdx.x;
  if (b < 12500) {
    if (b == 0) {          // one-time zeroing
      stats[tid] = 0.f;    // 256 floats
      if (tid < 32) zrow[tid] = 0.f;
    }
    long base = ((long)b * 256 + tid) * 4;
    const float4 v = *(const float4*)(x + base);
    bf16x4 o;
    o[0] = (bf16_t)v.x; o[1] = (bf16_t)v.y; o[2] = (bf16_t)v.z; o[3] = (bf16_t)v.w;
    *(bf16x4*)(xb + base) = o;
    return;
  }
  int b2 = b - 12500;
  const float* W = (b2 < 144) ? W1 : W2;
  bf16_t* Wp = (b2 < 144) ? W1p : W2p;
  if (b2 >= 144) b2 -= 144;
  int p = b2 * 256 + tid;           // [0, 36864)
  int j = p & 7;
  int lane = (p >> 3) & 63;
  int kstep = (p >> 9) & 1;
  int ntile = (p >> 10) & 3;
  int k = p >> 12;
  int col = ntile * 16 + (lane & 15);
  int kk = kstep * 32 + 8 * (lane >> 4) + j;
  Wp[p] = (bf16_t)W[(k * CC + kk) * CC + col];
}

// ---------------- conv: per-wave 32 rows x 64 cols, depth-3 gather pipeline ----------
// Wave wid owns rows [row0+32*wid, +32). A-fragments roll through a 4-slot register
// window (fully unrolled -> static indices); 12-16 gathers in flight per wave hide
// the ~700cy L2-miss latency. B-fragments (72KB packed W, L2-hot) double-buffered.
template <int OUT_F32>
__global__ __launch_bounds__(256, 3) void k_conv(
    const bf16_t* __restrict__ xb,   // NS x 64 bf16
    const int* __restrict__ nbr,     // NS x 9  (value NS == "no neighbor")
    const bf16_t* __restrict__ Wp,   // packed 9*4096 bf16
    void* __restrict__ yv,           // NS x 64 raw conv out
    float* __restrict__ stats,       // [128]: sum | sumsq
    const char* __restrict__ zrow)   // 128B of zeros (sentinel gather target)
{
  __shared__ int nbr_s[RPB * KF];    // 1152 ints
  __shared__ float lred[8 * CC];     // 4 waves x (sum|sq) x 64 cols

  const int tid = threadIdx.x;
  const int lane = tid & 63;
  const int wid = tid >> 6;
  const int row0 = blockIdx.x * RPB;
  const int l15 = lane & 15;
  const int lhi = lane >> 4;

  // stage this block's neighbor indices, bounds-clamped to sentinel NS
  {
    const long nbase = (long)row0 * KF;
    const long ntot = (long)NS * KF;
#pragma unroll
    for (int t = 0; t < 5; ++t) {
      int p = tid + t * 256;
      if (p < RPB * KF) {
        long g = nbase + p;
        nbr_s[p] = (g < ntot) ? nbr[g] : NS;
      }
    }
  }
  __syncthreads();

  const char* xbb = (const char*)xb;
  const bf16x8* wp = (const bf16x8*)Wp;
  const int r_lo = (32 * wid + l15) * KF;        // m=0 row base
  const int r_hi = (32 * wid + 16 + l15) * KF;   // m=1 row base

  auto rowptr = [&](int u) -> const char* {
    return ((unsigned)u < NS) ? (xbb + (size_t)(unsigned)u * 128u) : zrow;
  };

  // all 18 per-lane gather indices -> VGPRs
  int id0[KF], id1[KF];
#pragma unroll
  for (int k = 0; k < KF; ++k) { id0[k] = nbr_s[r_lo + k]; id1[k] = nbr_s[r_hi + k]; }

  f32x4 acc[2][4];
#pragma unroll
  for (int m = 0; m < 2; ++m)
#pragma unroll
    for (int n = 0; n < 4; ++n) acc[m][n] = (f32x4){0.f, 0.f, 0.f, 0.f};

  bf16x8 Af[4][2][2];          // [slot][m][kk] — 4-slot rolling window
  bf16x8 cB[4][2], nB[4][2];

  auto loadA = [&](int slot, int k) {
    const char* s0 = rowptr(id0[k]);
    const char* s1 = rowptr(id1[k]);
    Af[slot][0][0] = *(const bf16x8*)(s0 + lhi * 16);
    Af[slot][0][1] = *(const bf16x8*)(s0 + 64 + lhi * 16);
    Af[slot][1][0] = *(const bf16x8*)(s1 + lhi * 16);
    Af[slot][1][1] = *(const bf16x8*)(s1 + 64 + lhi * 16);
  };

  // prologue: B(k=0) first (consumed first), then A(k=0..2)
#pragma unroll
  for (int n = 0; n < 4; ++n)
#pragma unroll
    for (int kk = 0; kk < 2; ++kk)
      cB[n][kk] = wp[((0 * 4 + n) * 2 + kk) * 64 + lane];
#pragma unroll
  for (int k = 0; k < 3; ++k) loadA(k, k);

#pragma unroll
  for (int k = 0; k < KF; ++k) {
    if (k + 3 < KF) loadA((k + 3) & 3, k + 3);   // depth-3 A prefetch
    if (k + 1 < KF) {                             // depth-1 B prefetch (L2-hot)
#pragma unroll
      for (int n = 0; n < 4; ++n)
#pragma unroll
        for (int kk = 0; kk < 2; ++kk)
          nB[n][kk] = wp[(((k + 1) * 4 + n) * 2 + kk) * 64 + lane];
    }
    const int sl = k & 3;
    __builtin_amdgcn_s_setprio(1);
#pragma unroll
    for (int m = 0; m < 2; ++m)
#pragma unroll
      for (int n = 0; n < 4; ++n)
        acc[m][n] = __builtin_amdgcn_mfma_f32_16x16x32_bf16(Af[sl][m][0], cB[n][0], acc[m][n], 0, 0, 0);
#pragma unroll
    for (int m = 0; m < 2; ++m)
#pragma unroll
      for (int n = 0; n < 4; ++n)
        acc[m][n] = __builtin_amdgcn_mfma_f32_16x16x32_bf16(Af[sl][m][1], cB[n][1], acc[m][n], 0, 0, 0);
    __builtin_amdgcn_s_setprio(0);
#pragma unroll
    for (int n = 0; n < 4; ++n) { cB[n][0] = nB[n][0]; cB[n][1] = nB[n][1]; }
  }

  // epilogue: store y (guarded for tail block) + per-channel BN partials
  // C/D layout (m89): col = lane&15, row = 4*(lane>>4) + reg_idx (within 16x16 tile)
  float csum[4] = {0.f, 0.f, 0.f, 0.f}, csq[4] = {0.f, 0.f, 0.f, 0.f};
  bf16_t* yb = (bf16_t*)yv;
  float* yf = (float*)yv;
#pragma unroll
  for (int m = 0; m < 2; ++m) {
    const int rb0 = row0 + 32 * wid + 16 * m + 4 * lhi;
#pragma unroll
    for (int n = 0; n < 4; ++n) {
      const int col = 16 * n + l15;
#pragma unroll
      for (int j = 0; j < 4; ++j) {
        float v = acc[m][n][j];
        csum[n] += v; csq[n] += v * v;       // invalid rows contribute exact 0
        int rb = rb0 + j;
        if (rb < NS) {
          if (OUT_F32) yf[(long)rb * CC + col] = v;
          else         yb[(long)rb * CC + col] = (bf16_t)v;
        }
      }
    }
  }
#pragma unroll
  for (int n = 0; n < 4; ++n) {
    csum[n] += __shfl_xor(csum[n], 16); csum[n] += __shfl_xor(csum[n], 32);
    csq[n]  += __shfl_xor(csq[n], 16);  csq[n]  += __shfl_xor(csq[n], 32);
  }
  if (lane < 16) {
#pragma unroll
    for (int n = 0; n < 4; ++n) {
      lred[wid * CC + 16 * n + l15] = csum[n];
      lred[4 * CC + wid * CC + 16 * n + l15] = csq[n];
    }
  }
  __syncthreads();
  if (tid < CC) {
    float s = lred[tid] + lred[CC + tid] + lred[2 * CC + tid] + lred[3 * CC + tid];
    float q = lred[4 * CC + tid] + lred[5 * CC + tid] + lred[6 * CC + tid] + lred[7 * CC + tid];
    atomicAdd(&stats[tid], s);
    atomicAdd(&stats[64 + tid], q);
  }
}

// ---------------- BN(+ReLU) finalize folded in: each block recomputes scale/shift ----
__global__ void k_bnrelu(const bf16_t* __restrict__ in, const float* __restrict__ stats,
                         const float* __restrict__ gamma, const float* __restrict__ beta,
                         bf16_t* __restrict__ out) {
  __shared__ float ss_s[128];
  const int tid = threadIdx.x;
  if (tid < 64) {
    const float invN = 1.0f / (float)NS;
    float mean = stats[tid] * invN;
    float var = fmaxf(stats[64 + tid] * invN - mean * mean, 0.f);
    float rs = rsqrtf(var + 1e-5f);
    float sc = gamma[tid] * rs;
    ss_s[tid] = sc;
    ss_s[64 + tid] = beta[tid] - mean * sc;
  }
  __syncthreads();
  long base = ((long)blockIdx.x * 256 + tid) * 8;
  bf16x8 v = *(const bf16x8*)(in + base);
  int c0 = (int)(base & 63);
  bf16x8 o;
#pragma unroll
  for (int j = 0; j < 8; ++j) {
    float f = (float)v[j] * ss_s[c0 + j] + ss_s[64 + c0 + j];
    o[j] = (bf16_t)fmaxf(f, 0.f);
  }
  *(bf16x8*)(out + base) = o;
}

// ---------------- final: BN2 + residual, fp32, IN PLACE on d_out ----------------
__global__ void k_final(float* __restrict__ io, const float* __restrict__ stats,
                        const float* __restrict__ gamma, const float* __restrict__ beta,
                        const float* __restrict__ x) {
  __shared__ float ss_s[128];
  const int tid = threadIdx.x;
  if (tid < 64) {
    const float invN = 1.0f / (float)NS;
    float mean = stats[tid] * invN;
    float var = fmaxf(stats[64 + tid] * invN - mean * mean, 0.f);
    float rs = rsqrtf(var + 1e-5f);
    float sc = gamma[tid] * rs;
    ss_s[tid] = sc;
    ss_s[64 + tid] = beta[tid] - mean * sc;
  }
  __syncthreads();
  long base = ((long)blockIdx.x * 256 + tid) * 4;
  float4 v = *(const float4*)(io + base);
  float4 f = *(const float4*)(x + base);
  int c0 = (int)(base & 63);
  v.x = v.x * ss_s[c0 + 0] + ss_s[64 + c0 + 0] + f.x;
  v.y = v.y * ss_s[c0 + 1] + ss_s[64 + c0 + 1] + f.y;
  v.z = v.z * ss_s[c0 + 2] + ss_s[64 + c0 + 2] + f.z;
  v.w = v.w * ss_s[c0 + 3] + ss_s[64 + c0 + 3] + f.w;
  *(float4*)(io + base) = v;
}

extern "C" void kernel_launch(void* const* d_in, const int* in_sizes, int n_in,
                              void* d_out, int out_size, void* d_ws, size_t ws_size,
                              hipStream_t stream) {
  const float* features = (const float*)d_in[0];
  const int* nbr        = (const int*)d_in[1];
  const float* W1       = (const float*)d_in[2];
  const float* gamma1   = (const float*)d_in[3];
  const float* beta1    = (const float*)d_in[4];
  const float* W2       = (const float*)d_in[5];
  const float* gamma2   = (const float*)d_in[6];
  const float* beta2    = (const float*)d_in[7];

  // d_out doubles as scratch: phase 1 [xb bf16 | o1 bf16], phase 2 fp32 o2 in place.
  bf16_t* xb  = (bf16_t*)d_out;
  bf16_t* o1  = (bf16_t*)((char*)d_out + (size_t)NS * CC * 2);
  float*  o2f = (float*)d_out;

  // d_ws: y1n (25.6MB) + packed weights + stats + zero row
  char* ws = (char*)d_ws;
  auto alignup = [](size_t x) { return (x + 255) & ~(size_t)255; };
  size_t off = 0;
  bf16_t* y1n = (bf16_t*)(ws + off); off += alignup((size_t)NS * CC * 2);
  bf16_t* W1p = (bf16_t*)(ws + off); off += alignup((size_t)KF * 4096 * 2);
  bf16_t* W2p = (bf16_t*)(ws + off); off += alignup((size_t)KF * 4096 * 2);
  float* stats = (float*)(ws + off); off += alignup(256 * 4);  // stats1|stats2
  float* zrow  = (float*)(ws + off); off += alignup(32 * 4);   // 128B zeros

  k_prep<<<12500 + 288, 256, 0, stream>>>(features, W1, W2, xb, W1p, W2p, stats, zrow);

  k_conv<0><<<NB, 256, 0, stream>>>(xb, nbr, W1p, (void*)o1, stats, (const char*)zrow);
  k_bnrelu<<<6250, 256, 0, stream>>>(o1, stats, gamma1, beta1, y1n);

  k_conv<1><<<NB, 256, 0, stream>>>(y1n, nbr, W2p, (void*)o2f, stats + 128, (const char*)zrow);
  k_final<<<12500, 256, 0, stream>>>(o2f, stats + 128, gamma2, beta2, features);
}